// Round 13
// baseline (1211.781 us; speedup 1.0000x reference)
//
#include <hip/hip_runtime.h>
#include <hip/hip_bf16.h>
#include <stdint.h>

// Problem constants
#define BATCH_ 256
#define SEQ_   128
#define DIN_   768
#define HID_   512
#define NG_    2048   // 4*HID
#define NCLS_  9

typedef unsigned short u16;
typedef unsigned int u32;
typedef unsigned long long u64;
typedef __attribute__((ext_vector_type(8))) short bf16x8;
typedef __attribute__((ext_vector_type(4))) float f32x4;

__device__ __forceinline__ float bf2f(u16 u) {
  return __builtin_bit_cast(float, (uint32_t)u << 16);
}
__device__ __forceinline__ u16 f2bf(float f) {
  uint32_t x = __builtin_bit_cast(uint32_t, f);
  uint32_t r = (x + 0x7fffu + ((x >> 16) & 1u)) >> 16;  // RNE
  return (u16)r;
}

__device__ __forceinline__ u32 aload32(const u32* p) {
  return __hip_atomic_load(p, __ATOMIC_RELAXED, __HIP_MEMORY_SCOPE_AGENT);
}
__device__ __forceinline__ void astore32(u32* p, u32 v) {
  __hip_atomic_store(p, v, __ATOMIC_RELAXED, __HIP_MEMORY_SCOPE_AGENT);
}

// ---------------- f32 -> bf16 cast (weights) ----------------
__global__ void castk(const float* __restrict__ s, u16* __restrict__ d, int n4) {
  int i = blockIdx.x * blockDim.x + threadIdx.x;
  if (i < n4) {
    float4 v = ((const float4*)s)[i];
    ushort4 o;
    o.x = f2bf(v.x); o.y = f2bf(v.y); o.z = f2bf(v.z); o.w = f2bf(v.w);
    ((ushort4*)d)[i] = o;
  }
}

// ---------------- embed gather + add pos + cast, (S,B,768) bf16 ----------------
__global__ __launch_bounds__(192) void embed_k(const int* __restrict__ ids,
                                               const float* __restrict__ tok,
                                               const float* __restrict__ pos,
                                               u16* __restrict__ X) {
  const int row = blockIdx.x;          // row = t*256 + b
  const int t = row >> 8, b = row & 255;
  const int id = ids[b * SEQ_ + t];    // input_ids is (B,S)
  const float4* tr = (const float4*)(tok + (size_t)id * DIN_);
  const float4* pr = (const float4*)(pos + (size_t)t * DIN_);
  const int i = threadIdx.x;
  float4 v = tr[i], p = pr[i];
  ushort4 o;
  o.x = f2bf(v.x + p.x); o.y = f2bf(v.y + p.y);
  o.z = f2bf(v.z + p.z); o.w = f2bf(v.w + p.w);
  ((ushort4*)(X + (size_t)row * DIN_))[i] = o;
}

// stage 32 rows x 512 cols bf16 (row stride 512) into LDS, XOR-swizzled.
// PLAIN cached loads (R10-R12-proven safe & fast for write-once NT-stored h).
__device__ __forceinline__ void stage32r(char* dst, const u16* src, int tid) {
  const u64* s64 = (const u64*)src;
#pragma unroll
  for (int i = 0; i < 8; ++i) {
    int e = i * 512 + tid, r = e >> 7, c8 = e & 127;
    u64 v = s64[(size_t)r * 128 + c8];
    *(u64*)(dst + r * 1024 + ((((c8 >> 1) ^ (r & 7)) << 4) | ((c8 & 1) << 3))) = v;
  }
}

// stage 32 rows x 768 cols bf16 (row stride 768) into LDS, XOR-swizzled.
__device__ __forceinline__ void stage32x(char* dst, const u16* src, int tid) {
  const u64* s64 = (const u64*)src;
#pragma unroll
  for (int i = 0; i < 12; ++i) {
    int e = i * 512 + tid;
    int r = e / 192, c8 = e - r * 192;      // 192 u64 per row
    u64 v = s64[(size_t)r * 192 + c8];
    int c16 = c8 >> 1, lo = c8 & 1;
    *(u64*)(dst + r * 1536 + (((c16 ^ (r & 7)) << 4) | (lo << 3))) = v;
  }
}

// ---------------- fused full-LSTM wavefront kernel, v6 ----------------
// 256 blocks (cooperative, 1/CU via 113KB LDS), 512 threads.
// Tile: 32 batch rows (m8) x 32 hid cols (j16) x 4 gates.
//   bid [0,128):   L1 — h1(t) = act(W1 x(t) + R1 h1(t-1) + b1)
//   bid [128,256): L2 — h2(t) = act(W2 h1(t) + R2 h2(t-1) + b2)
// NEW vs R12 (passed, 615us + 188us gemm): phase-A GEMM is FOLDED IN. L1 holds
// W1 (96 VGPR/lane) + R1 (64) and computes W1·x(t) BEFORE polling for h(t-1) —
// x(t) has no chain dependence, so that work hides in the poll slack the
// wavefront forces anyway. Xpre buffer + gemm dispatch + one bf16 rounding gone.
// 8 waves = (gate g = w&3, kh = w>>2): L1 kh = K-half of both W1 (12 ksteps) and
// R1 (8 ksteps); L2 kh selects matrix (W2 vs R2), kh-partial Gs sum = concat.
// Sync protocol verbatim R12: NT h-stores -> barrier vmcnt drain -> counter
// atomicAdd; consumer single-address poll >=16; PLAIN cached stage loads.
__global__ __launch_bounds__(512, 2) void lstm_duo4(
    const u16* __restrict__ Xemb,    // (S,256,768) bf16 embeds
    u16* __restrict__ H1,            // (S,256,512)
    u16* __restrict__ H2,            // (S,256,512)
    const u16* __restrict__ W1b,     // (2048,768)
    const u16* __restrict__ R1b,     // (2048,512)
    const u16* __restrict__ W2b,     // (2048,512)
    const u16* __restrict__ R2b,     // (2048,512)
    const float* __restrict__ b1,    // (2048,)
    const float* __restrict__ b2,    // (2048,)
    u32* __restrict__ cnt1, u32* __restrict__ cnt2) {   // [SEQ][8] counters
  __shared__ __align__(16) char lds[115712];
  // L1 layout: Xs [0,49152) | h [49152,81920) | Gs [81920,115712)
  // L2 layout: As1 [0,32768) | As2 [32768,65536) | Gs [81920,115712)
  const int tid = threadIdx.x;
  const int lane = tid & 63;
  const int w = tid >> 6;
  const int lr = lane & 15, lg = lane >> 4;
  const int kind = blockIdx.x >> 7;            // 0=L1, 1=L2
  const int lb = blockIdx.x & 127;
  const int m8 = lb & 7, j16 = lb >> 3;
  const int m0 = m8 * 32, j0 = j16 * 32;
  const int g = w & 3, kh = w >> 2;
  const int cr = tid >> 4, cc = (tid & 15) * 2;   // epilogue cell ownership
  float* Gsf = (float*)(lds + 81920);
#define GS(KH, GG, RR, CC) Gsf[(((KH) * 4 + (GG)) * 32 + (RR)) * 33 + (CC)]

  if (kind == 0) {
    // =========================== L1 ===========================
    char* Xs = lds;
    char* Ash = lds + 49152;
    // W1 frags: gate g, cols j0+nf*16+lr, kh-half of K=768 (12 ksteps) -> 96 VGPR
    bf16x8 Wx[2][12];
#pragma unroll
    for (int nf = 0; nf < 2; ++nf)
#pragma unroll
      for (int k = 0; k < 12; ++k)
        Wx[nf][k] = *(const bf16x8*)&W1b[(size_t)(g * 512 + j0 + nf * 16 + lr) * 768 +
                                         kh * 384 + k * 32 + lg * 8];
    // R1 frags: kh-half of K=512 (8 ksteps) -> 64 VGPR
    bf16x8 B1[2][8];
#pragma unroll
    for (int nf = 0; nf < 2; ++nf)
#pragma unroll
      for (int k = 0; k < 8; ++k)
        B1[nf][k] = *(const bf16x8*)&R1b[(size_t)(g * 512 + j0 + nf * 16 + lr) * 512 +
                                         kh * 256 + k * 32 + lg * 8];
    float bc[4][2];
#pragma unroll
    for (int gg = 0; gg < 4; ++gg) {
      bc[gg][0] = b1[gg * 512 + j0 + cc];
      bc[gg][1] = b1[gg * 512 + j0 + cc + 1];
    }
    float cst0 = 0.f, cst1 = 0.f;

    for (int t = 0; t < SEQ_; ++t) {
      // (A) stage x(t) — no chain dependence
      stage32x(Xs, Xemb + ((size_t)t * BATCH_ + m0) * DIN_, tid);
      __syncthreads();                       // B1: Xs ready
      // (B) W1·x MFMAs — runs in the slack before h(t-1) is ready
      f32x4 acc[2][2] = {};
#pragma unroll
      for (int k = 0; k < 12; ++k) {
        int c = kh * 48 + k * 4 + lg;
        int sw = ((c ^ (lr & 7)) << 4);
        bf16x8 a0 = *(const bf16x8*)(Xs + lr * 1536 + sw);
        bf16x8 a1 = *(const bf16x8*)(Xs + (16 + lr) * 1536 + sw);
        acc[0][0] = __builtin_amdgcn_mfma_f32_16x16x32_bf16(a0, Wx[0][k], acc[0][0], 0, 0, 0);
        acc[0][1] = __builtin_amdgcn_mfma_f32_16x16x32_bf16(a0, Wx[1][k], acc[0][1], 0, 0, 0);
        acc[1][0] = __builtin_amdgcn_mfma_f32_16x16x32_bf16(a1, Wx[0][k], acc[1][0], 0, 0, 0);
        acc[1][1] = __builtin_amdgcn_mfma_f32_16x16x32_bf16(a1, Wx[1][k], acc[1][1], 0, 0, 0);
      }
      // (C) poll for h1(t-1)
      if (t > 0 && w == 0 && lane == 0) {
        const u32* f = cnt1 + (size_t)(t - 1) * 8 + m8;
        int spins = 0;
        while (aload32(f) < 16u) {
          __builtin_amdgcn_s_sleep(1);
          if (++spins > (1 << 21)) break;
        }
      }
      __syncthreads();                       // B2: poll done
      if (t > 0) {
        stage32r(Ash, H1 + ((size_t)(t - 1) * BATCH_ + m0) * HID_, tid);
      }
      __syncthreads();                       // B3: h ready
      if (t > 0) {
#pragma unroll
        for (int k = 0; k < 8; ++k) {
          int c = kh * 32 + k * 4 + lg;
          int sw = ((c ^ (lr & 7)) << 4);
          bf16x8 a0 = *(const bf16x8*)(Ash + lr * 1024 + sw);
          bf16x8 a1 = *(const bf16x8*)(Ash + (16 + lr) * 1024 + sw);
          acc[0][0] = __builtin_amdgcn_mfma_f32_16x16x32_bf16(a0, B1[0][k], acc[0][0], 0, 0, 0);
          acc[0][1] = __builtin_amdgcn_mfma_f32_16x16x32_bf16(a0, B1[1][k], acc[0][1], 0, 0, 0);
          acc[1][0] = __builtin_amdgcn_mfma_f32_16x16x32_bf16(a1, B1[0][k], acc[1][0], 0, 0, 0);
          acc[1][1] = __builtin_amdgcn_mfma_f32_16x16x32_bf16(a1, B1[1][k], acc[1][1], 0, 0, 0);
        }
      }
      // publish kh-partials (C/D: col=lane&15, row=(lane>>4)*4+q)
#pragma unroll
      for (int mf = 0; mf < 2; ++mf)
#pragma unroll
        for (int nf = 0; nf < 2; ++nf)
#pragma unroll
          for (int q = 0; q < 4; ++q)
            GS(kh, g, mf * 16 + lg * 4 + q, nf * 16 + lr) = acc[mf][nf][q];
      __syncthreads();                       // B4: Gs ready
      {  // cell update: thread owns (cr, cc..cc+1)
        float G[4][2];
#pragma unroll
        for (int gg = 0; gg < 4; ++gg) {
          G[gg][0] = GS(0, gg, cr, cc) + GS(1, gg, cr, cc) + bc[gg][0];
          G[gg][1] = GS(0, gg, cr, cc + 1) + GS(1, gg, cr, cc + 1) + bc[gg][1];
        }
        u32 pack = 0;
        {
          float iv = 1.f / (1.f + expf(-G[0][0]));
          float fv = 1.f / (1.f + expf(-G[1][0]));
          float mv = tanhf(G[2][0]);
          float ov = 1.f / (1.f + expf(-G[3][0]));
          float cn = mv * iv + fv * cst0; cst0 = cn;
          pack |= (u32)f2bf(ov * tanhf(cn));
        }
        {
          float iv = 1.f / (1.f + expf(-G[0][1]));
          float fv = 1.f / (1.f + expf(-G[1][1]));
          float mv = tanhf(G[2][1]);
          float ov = 1.f / (1.f + expf(-G[3][1]));
          float cn = mv * iv + fv * cst1; cst1 = cn;
          pack |= (u32)f2bf(ov * tanhf(cn)) << 16;
        }
        astore32((u32*)(H1 + (size_t)t * (BATCH_ * HID_) +
                        (size_t)(m0 + cr) * HID_ + j0 + cc), pack);  // NT -> MALL
      }
      __syncthreads();                       // B5: vmcnt(0) drain before counter
      if (tid == 0)
        __hip_atomic_fetch_add(cnt1 + (size_t)t * 8 + m8, 1u,
                               __ATOMIC_RELAXED, __HIP_MEMORY_SCOPE_AGENT);
    }
  } else {
    // =========================== L2 (verbatim R12) ===========================
    char* As1 = lds;
    char* As2 = lds + 32768;
    const u16* Bmat = kh ? R2b : W2b;
    bf16x8 Bw[2][16];
#pragma unroll
    for (int nf = 0; nf < 2; ++nf)
#pragma unroll
      for (int k = 0; k < 16; ++k)
        Bw[nf][k] = *(const bf16x8*)&Bmat[(size_t)(g * 512 + j0 + nf * 16 + lr) * 512 +
                                          k * 32 + lg * 8];
    float bc[4][2];
#pragma unroll
    for (int gg = 0; gg < 4; ++gg) {
      bc[gg][0] = b2[gg * 512 + j0 + cc];
      bc[gg][1] = b2[gg * 512 + j0 + cc + 1];
    }
    float cst0 = 0.f, cst1 = 0.f;

    for (int t = 0; t < SEQ_; ++t) {
      if (w == 0) {   // lane0: cnt1[t] (h1 ready), lane1: cnt2[t-1] (self)
        const u32* fa = cnt1 + (size_t)t * 8 + m8;
        const u32* fb = cnt2 + (size_t)(t > 0 ? t - 1 : 0) * 8 + m8;
        int spins = 0;
        while (true) {
          bool ok = true;
          if (lane == 0) ok = aload32(fa) >= 16u;
          else if (lane == 1) ok = (t == 0) || (aload32(fb) >= 16u);
          if (__all(ok)) break;
          __builtin_amdgcn_s_sleep(1);
          if (++spins > (1 << 21)) break;
        }
      }
      __syncthreads();
      stage32r(As1, H1 + ((size_t)t * BATCH_ + m0) * HID_, tid);
      if (t > 0)
        stage32r(As2, H2 + ((size_t)(t - 1) * BATCH_ + m0) * HID_, tid);
      __syncthreads();
      f32x4 acc[2][2] = {};
      if (kh == 0 || t > 0) {
        const char* As = kh ? As2 : As1;
#pragma unroll
        for (int k = 0; k < 16; ++k) {
          int c = k * 4 + lg;
          int sw = ((c ^ (lr & 7)) << 4);
          bf16x8 a0 = *(const bf16x8*)(As + (lr) * 1024 + sw);
          bf16x8 a1 = *(const bf16x8*)(As + (16 + lr) * 1024 + sw);
          acc[0][0] = __builtin_amdgcn_mfma_f32_16x16x32_bf16(a0, Bw[0][k], acc[0][0], 0, 0, 0);
          acc[0][1] = __builtin_amdgcn_mfma_f32_16x16x32_bf16(a0, Bw[1][k], acc[0][1], 0, 0, 0);
          acc[1][0] = __builtin_amdgcn_mfma_f32_16x16x32_bf16(a1, Bw[0][k], acc[1][0], 0, 0, 0);
          acc[1][1] = __builtin_amdgcn_mfma_f32_16x16x32_bf16(a1, Bw[1][k], acc[1][1], 0, 0, 0);
        }
      }
#pragma unroll
      for (int mf = 0; mf < 2; ++mf)
#pragma unroll
        for (int nf = 0; nf < 2; ++nf)
#pragma unroll
          for (int q = 0; q < 4; ++q)
            GS(kh, g, mf * 16 + lg * 4 + q, nf * 16 + lr) = acc[mf][nf][q];
      __syncthreads();
      {
        float G[4][2];
#pragma unroll
        for (int gg = 0; gg < 4; ++gg) {
          G[gg][0] = GS(0, gg, cr, cc) + GS(1, gg, cr, cc) + bc[gg][0];
          G[gg][1] = GS(0, gg, cr, cc + 1) + GS(1, gg, cr, cc + 1) + bc[gg][1];
        }
        u32 pack = 0;
        {
          float iv = 1.f / (1.f + expf(-G[0][0]));
          float fv = 1.f / (1.f + expf(-G[1][0]));
          float mv = tanhf(G[2][0]);
          float ov = 1.f / (1.f + expf(-G[3][0]));
          float cn = mv * iv + fv * cst0; cst0 = cn;
          pack |= (u32)f2bf(ov * tanhf(cn));
        }
        {
          float iv = 1.f / (1.f + expf(-G[0][1]));
          float fv = 1.f / (1.f + expf(-G[1][1]));
          float mv = tanhf(G[2][1]);
          float ov = 1.f / (1.f + expf(-G[3][1]));
          float cn = mv * iv + fv * cst1; cst1 = cn;
          pack |= (u32)f2bf(ov * tanhf(cn)) << 16;
        }
        astore32((u32*)(H2 + (size_t)t * (BATCH_ * HID_) +
                        (size_t)(m0 + cr) * HID_ + j0 + cc), pack);
      }
      __syncthreads();
      if (tid == 0)
        __hip_atomic_fetch_add(cnt2 + (size_t)t * 8 + m8, 1u,
                               __ATOMIC_RELAXED, __HIP_MEMORY_SCOPE_AGENT);
    }
  }
#undef GS
}

// ---------------- output projection: out[b][t][cls] = h2 . Wo[cls] + bo ----------------
__global__ __launch_bounds__(320) void out_proj(const u16* __restrict__ H2,
                                                const float* __restrict__ Wo,
                                                const float* __restrict__ bo,
                                                float* __restrict__ out) {
  __shared__ __align__(16) u16 Hs[32 * 520];
  const int r0 = blockIdx.x * 32;     // flat row = t*256 + b
  const int tid = threadIdx.x;
  for (int e = tid; e < 2048; e += 320) {
    int rl = e >> 6, k8 = (e & 63) * 8;
    *(uint4*)&Hs[rl * 520 + k8] = *(const uint4*)(H2 + (size_t)(r0 + rl) * HID_ + k8);
  }
  __syncthreads();
  if (tid < 288) {
    int rl = tid / 9, cls = tid - rl * 9;
    const u16* h = &Hs[rl * 520];
    const float* wv = Wo + cls * HID_;
    float s = bo[cls];
#pragma unroll 8
    for (int k = 0; k < HID_; ++k) s += bf2f(h[k]) * wv[k];
    int r = r0 + rl, t = r >> 8, b = r & 255;
    out[((size_t)b * SEQ_ + t) * NCLS_ + cls] = s;
  }
}

extern "C" void kernel_launch(void* const* d_in, const int* in_sizes, int n_in,
                              void* d_out, int out_size, void* d_ws, size_t ws_size,
                              hipStream_t stream) {
  (void)in_sizes; (void)n_in; (void)out_size; (void)ws_size;
  const int*   ids = (const int*)d_in[0];
  const float* tok = (const float*)d_in[1];
  const float* pos = (const float*)d_in[2];
  const float* W1  = (const float*)d_in[3];
  const float* R1  = (const float*)d_in[4];
  const float* b1  = (const float*)d_in[5];
  const float* W2  = (const float*)d_in[6];
  const float* R2  = (const float*)d_in[7];
  const float* b2  = (const float*)d_in[8];
  const float* Wo  = (const float*)d_in[9];
  const float* bo  = (const float*)d_in[10];
  float* out = (float*)d_out;

  // workspace (~124 MB)
  char* p = (char*)d_ws;
  auto alloc = [&](size_t bytes) { char* q = p; p += (bytes + 255) & ~(size_t)255; return q; };
  u16*  W1b  = (u16*)alloc((size_t)NG_ * DIN_ * 2);                 // 3MB
  u16*  R1b  = (u16*)alloc((size_t)NG_ * HID_ * 2);                 // 2MB
  u16*  W2b  = (u16*)alloc((size_t)NG_ * HID_ * 2);                 // 2MB
  u16*  R2b  = (u16*)alloc((size_t)NG_ * HID_ * 2);                 // 2MB
  u32*  cnt1 = (u32*)alloc((size_t)SEQ_ * 8 * 4);                   // 4KB
  u32*  cnt2 = (u32*)alloc((size_t)SEQ_ * 8 * 4);                   // 4KB
  u16*  Xemb = (u16*)alloc((size_t)SEQ_ * BATCH_ * DIN_ * 2);       // 50.3MB (live all steps)
  u16*  H1all = (u16*)alloc((size_t)SEQ_ * BATCH_ * HID_ * 2);      // 32MB
  u16*  H2all = (u16*)alloc((size_t)SEQ_ * BATCH_ * HID_ * 2);      // 32MB

  // weight casts
  castk<<<dim3((NG_ * DIN_ / 4 + 255) / 256), 256, 0, stream>>>(W1, W1b, NG_ * DIN_ / 4);
  castk<<<dim3((NG_ * HID_ / 4 + 255) / 256), 256, 0, stream>>>(R1, R1b, NG_ * HID_ / 4);
  castk<<<dim3((NG_ * HID_ / 4 + 255) / 256), 256, 0, stream>>>(W2, W2b, NG_ * HID_ / 4);
  castk<<<dim3((NG_ * HID_ / 4 + 255) / 256), 256, 0, stream>>>(R2, R2b, NG_ * HID_ / 4);
  // counters must be zero each call (graph replays re-run this memset)
  hipMemsetAsync(cnt1, 0, (size_t)2 * SEQ_ * 8 * 4, stream);  // cnt1+cnt2 contiguous

  // embeds -> (S,B,768) bf16
  embed_k<<<dim3(SEQ_ * BATCH_), 192, 0, stream>>>(ids, tok, pos, Xemb);

  // fused full-LSTM wavefront (cooperative: co-residency for spin-wait)
  {
    const u16* Xp = Xemb; u16* H1a = H1all; u16* H2a = H2all;
    const u16* W1a = W1b; const u16* R1a = R1b;
    const u16* W2a = W2b; const u16* R2a = R2b;
    const float* b1a = b1; const float* b2a = b2;
    u32* c1 = cnt1; u32* c2 = cnt2;
    void* args[] = {(void*)&Xp, (void*)&H1a, (void*)&H2a, (void*)&W1a, (void*)&R1a,
                    (void*)&W2a, (void*)&R2a, (void*)&b1a, (void*)&b2a,
                    (void*)&c1, (void*)&c2};
    hipLaunchCooperativeKernel(reinterpret_cast<void*>(&lstm_duo4),
                               dim3(256), dim3(512), args, 0, stream);
  }

  // logits
  out_proj<<<dim3(SEQ_ * BATCH_ / 32), 320, 0, stream>>>(H2all, Wo, bo, out);
}